// Round 3
// baseline (94.962 us; speedup 1.0000x reference)
//
#include <hip/hip_runtime.h>

#define HH 2048
#define WW 2048
#define NB 1024
#define TW 256  // tile width
#define TH 16   // tile height
// 256 threads/block = 4 waves. Wave w owns rows py0 = tileY + w*4 .. +3.
// Lane owns 4 consecutive x: px0 = tileX + lane*4. Each float4 store is
// 64 lanes x 16 B = 1 KB contiguous (single row segment) -> ideal coalescing.

__global__ __launch_bounds__(256, 4) void paint_kernel(const float4* __restrict__ boxes,
                                                       float* __restrict__ out) {
    __shared__ unsigned long long imaskS[4][4];  // [chunk][wave]
    __shared__ unsigned long long fmaskS[4][4];
    __shared__ uint2  clist[NB];   // packed pixel coords of pruned candidates
    __shared__ float4 clistV[NB];  // their normalized float values

    const int tid  = threadIdx.x;
    const int lane = tid & 63;
    const int wid  = tid >> 6;
    const int tileX = blockIdx.x * TW;
    const int tileY = blockIdx.y * TH;

    // ---- pass 1: load + convert + ballot; everything stays in registers ----
    float4 bx[4];
    int ry1[4], rx1[4], ry2[4], rx2[4];
    bool rint[4];
    #pragma unroll
    for (int c = 0; c < 4; ++c) {
        bx[c] = boxes[c * 256 + tid];
        int y1 = max(0, (int)(bx[c].x * (float)HH));  // trunc == astype(int32)
        int x1 = max(0, (int)(bx[c].y * (float)WW));
        int y2 = min(HH, (int)(bx[c].z * (float)HH));
        int x2 = min(WW, (int)(bx[c].w * (float)WW));
        ry1[c] = y1; rx1[c] = x1; ry2[c] = y2; rx2[c] = x2;
        bool valid = (y1 < y2) && (x1 < x2);
        bool inter = valid && (y1 < tileY + TH) && (y2 > tileY) &&
                     (x1 < tileX + TW) && (x2 > tileX);
        bool full  = (y1 <= tileY) && (y2 >= tileY + TH) &&
                     (x1 <= tileX) && (x2 >= tileX + TW);
        rint[c] = inter;
        unsigned long long mi = __ballot(inter);
        unsigned long long mf = __ballot(full);
        if (lane == 0) { imaskS[c][wid] = mi; fmaskS[c][wid] = mf; }
    }
    __syncthreads();  // barrier 1

    // ---- lastFull: highest-index box fully covering the tile (block-uniform) ----
    int lastFull = -1;
    #pragma unroll
    for (int c = 3; c >= 0; --c)
        #pragma unroll
        for (int w = 3; w >= 0; --w)
            if (lastFull < 0) {
                unsigned long long m = fmaskS[c][w];
                if (m) lastFull = c * 256 + w * 64 + 63 - __clzll(m);
            }

    // ---- prune intersect masks to idx > lastFull; exclusive-scan offsets ----
    int cnt_all = 0;
    int myoff[4];
    #pragma unroll
    for (int c = 0; c < 4; ++c) {
        #pragma unroll
        for (int w = 0; w < 4; ++w) {
            unsigned long long m = imaskS[c][w];
            int d = lastFull - (c * 256 + w * 64);
            if (d >= 63) m = 0;
            else if (d >= 0) m &= (~0ull) << (d + 1);
            if (w == wid)
                myoff[c] = cnt_all + __popcll(m & ((1ull << lane) - 1ull));
            cnt_all += __popcll(m);
        }
    }

    // ---- sparse compaction (coords + values; list order == paint order) ----
    #pragma unroll
    for (int c = 0; c < 4; ++c) {
        int b = c * 256 + tid;
        if (rint[c] && b > lastFull) {
            clist[myoff[c]]  = make_uint2(((unsigned)ry1[c] << 16) | (unsigned)rx1[c],
                                          ((unsigned)ry2[c] << 16) | (unsigned)rx2[c]);
            clistV[myoff[c]] = bx[c];
        }
    }
    __syncthreads();  // barrier 2

    // default fill = lastFull box (block-uniform)
    float4 bvLast = make_float4(0.f, 0.f, 0.f, 0.f);
    float  onLast = 0.f;
    if (lastFull >= 0) { bvLast = boxes[lastFull]; onLast = 1.f; }

    const int px0 = tileX + lane * 4;
    const int py0 = tileY + wid * 4;

    if (cnt_all == 0) {
        // ---- uniform fast path ----
        float vals[5] = {onLast, bvLast.x, bvLast.y, bvLast.z, bvLast.w};
        #pragma unroll
        for (int ch = 0; ch < 5; ++ch) {
            float4 v = make_float4(vals[ch], vals[ch], vals[ch], vals[ch]);
            size_t base = (size_t)ch * (HH * WW);
            #pragma unroll
            for (int s = 0; s < 4; ++s)
                *(float4*)(out + base + (size_t)(py0 + s) * WW + px0) = v;
        }
    } else {
        // ---- per-pixel ownership: ascending overwrite over tiny pruned list;
        //      fnd = winning LIST index (later j wins == paint order) ----
        int fnd[4][4];
        #pragma unroll
        for (int s = 0; s < 4; ++s)
            #pragma unroll
            for (int k = 0; k < 4; ++k) fnd[s][k] = -1;
        for (int j = 0; j < cnt_all; ++j) {
            uint2 pc = clist[j];  // one ds_read_b64, broadcast
            int by1 = (int)(pc.x >> 16), bx1 = (int)(pc.x & 0xffff);
            int by2 = (int)(pc.y >> 16), bx2 = (int)(pc.y & 0xffff);
            #pragma unroll
            for (int s = 0; s < 4; ++s) {
                int py = py0 + s;
                bool yin = (py >= by1) && (py < by2);
                #pragma unroll
                for (int k = 0; k < 4; ++k) {
                    int px = px0 + k;
                    if (yin && px >= bx1 && px < bx2) fnd[s][k] = j;
                }
            }
        }
        #pragma unroll
        for (int s = 0; s < 4; ++s) {
            float4 v[5];
            #pragma unroll
            for (int k = 0; k < 4; ++k) {
                int f = fnd[s][k];
                float4 bv = (f >= 0) ? clistV[f] : bvLast;  // LDS, few distinct f
                float on  = (f >= 0) ? 1.f : onLast;
                ((float*)&v[0])[k] = on;
                ((float*)&v[1])[k] = bv.x;
                ((float*)&v[2])[k] = bv.y;
                ((float*)&v[3])[k] = bv.z;
                ((float*)&v[4])[k] = bv.w;
            }
            size_t pb = (size_t)(py0 + s) * WW + px0;
            #pragma unroll
            for (int ch = 0; ch < 5; ++ch)
                *(float4*)(out + (size_t)ch * (HH * WW) + pb) = v[ch];
        }
    }
}

extern "C" void kernel_launch(void* const* d_in, const int* in_sizes, int n_in,
                              void* d_out, int out_size, void* d_ws, size_t ws_size,
                              hipStream_t stream) {
    const float4* boxes = (const float4*)d_in[0];
    float* out = (float*)d_out;
    dim3 grid(WW / TW, HH / TH);  // 8 x 128 = 1024 blocks
    dim3 block(256);
    paint_kernel<<<grid, block, 0, stream>>>(boxes, out);
}